// Round 23
// baseline (2100.281 us; speedup 1.0000x reference)
//
#include <hip/hip_runtime.h>
#include <math.h>

// CTC prefix beam search, TWO examples per block, 16-LANE-ROW layout.
// R23 = R20 with the iterative 16-round selection REPLACED by one bitonic
// tournament sort: insert stay into the sorted stream (truncate 16), then 4
// DPP merge levels (half-clean + 4-stage bitonic clean) leave the global
// sorted top-16 in every lane; beam bm extracts rank bm via a select tree.
// Exact: keys distinct => sort == (score,~idx) order == jax.lax.top_k order.
// Numerics replicate XLA:CPU f32 op-for-op (verified absmax 0.0 r3-r22).
#define NBATCH 512
#define TSTEPS 512
#define VCLS   96
#define CCLS   95
#define BWID   16
#define VPAD   104
#define NEGF   (-1e30f)

typedef unsigned long long u64;
typedef unsigned int u32;

// ---------------- XLA:CPU-replica transcendentals (no FMA, explicit rounding) ----------------
__device__ __forceinline__ float exp_xla(float x){
    x = fminf(x, 88.3762626647950f);
    x = fmaxf(x, -88.3762626647949f);
    float t = __fadd_rn(__fmul_rn(x, 1.44269504088896341f), 0.5f);
    float m = floorf(t);
    float r = __fadd_rn(__fmul_rn(m, -0.693359375f), x);
    r = __fadd_rn(__fmul_rn(m, 2.12194440e-4f), r);
    float y = 1.9875691500E-4f;
    y = __fadd_rn(__fmul_rn(y, r), 1.3981999507E-3f);
    y = __fadd_rn(__fmul_rn(y, r), 8.3334519073E-3f);
    y = __fadd_rn(__fmul_rn(y, r), 4.1665795894E-2f);
    y = __fadd_rn(__fmul_rn(y, r), 1.6666665459E-1f);
    y = __fadd_rn(__fmul_rn(y, r), 5.0000001201E-1f);
    float r2 = __fmul_rn(r, r);
    y = __fadd_rn(__fmul_rn(y, r2), r);
    y = __fadd_rn(y, 1.0f);
    int n = (int)m;
    unsigned sb = (unsigned)(n + 127);
    float s = __uint_as_float(sb << 23);
    return __fmul_rn(y, s);
}

__device__ __forceinline__ float log_xla(float x){
    unsigned bits = __float_as_uint(x);
    int e = (int)(bits >> 23) - 126;
    float m = __uint_as_float((bits & 0x007FFFFFu) | 0x3F000000u);
    if (m < 0.707106781186547524f){
        e -= 1;
        m = __fsub_rn(__fadd_rn(m, m), 1.0f);
    } else {
        m = __fsub_rn(m, 1.0f);
    }
    float z = __fmul_rn(m, m);
    float p = 7.0376836292E-2f;
    p = __fadd_rn(__fmul_rn(p, m), -1.1514610310E-1f);
    p = __fadd_rn(__fmul_rn(p, m),  1.1676998740E-1f);
    p = __fadd_rn(__fmul_rn(p, m), -1.2420140846E-1f);
    p = __fadd_rn(__fmul_rn(p, m),  1.4249322787E-1f);
    p = __fadd_rn(__fmul_rn(p, m), -1.6668057665E-1f);
    p = __fadd_rn(__fmul_rn(p, m),  2.0000714765E-1f);
    p = __fadd_rn(__fmul_rn(p, m), -2.4999993993E-1f);
    p = __fadd_rn(__fmul_rn(p, m),  3.3333331174E-1f);
    float y = __fmul_rn(m, __fmul_rn(z, p));
    float fe = (float)e;
    y = __fadd_rn(y, __fmul_rn(-2.12194440e-4f, fe));
    y = __fadd_rn(y, __fmul_rn(-0.5f, z));
    float rr = __fadd_rn(m, y);
    rr = __fadd_rn(rr, __fmul_rn(0.693359375f, fe));
    return rr;
}

__device__ __forceinline__ float log1p_xla(float x){
    float u = __fadd_rn(x, 1.0f);
    if (u == 1.0f) return x;
    float lu = log_xla(u);
    float um1 = __fsub_rn(u, 1.0f);
    return __fmul_rn(lu, __fdiv_rn(x, um1));
}

__device__ __forceinline__ float logaddexp_x(float x, float y){
    float amax = fmaxf(x, y);
    float d = __fsub_rn(x, y);
    float e = exp_xla(-fabsf(d));
    float l1p = log1p_xla(e);
    return __fadd_rn(amax, l1p);
}

// monotone float -> uint (ascending); no NaN/-0 candidates by construction
__device__ __forceinline__ unsigned ford(float f){
    unsigned u = __float_as_uint(f);
    return (u & 0x80000000u) ? ~u : (u | 0x80000000u);
}
__device__ __forceinline__ float unford(u32 u){
    return __uint_as_float((u & 0x80000000u) ? (u ^ 0x80000000u) : ~u);
}

// ---------------- f64-packed selection keys ----------------
__device__ __forceinline__ double packkey(float sc, int k){
    u64 kb = ((u64)ford(sc) << 31) | ((u64)((~(u32)k) & 0x7FFu) << 20);
    return __longlong_as_double((long long)kb);
}
__device__ __forceinline__ int decodekey(double wk){
    u32 idxinv = (u32)((u64)__double_as_longlong(wk) >> 20) & 0x7FFu;
    return (int)((~idxinv) & 0x7FFu);
}
__device__ __forceinline__ double packlp(float v, int c){
    u64 kb = ((u64)ford(v) << 31) | ((u64)((~(u32)c) & 0x7Fu) << 24);
    return __longlong_as_double((long long)kb);
}

// ---------------- intra-wave LDS fence ----------------
__device__ __forceinline__ void wave_fence(){
    asm volatile("s_waitcnt lgkmcnt(0)" ::: "memory");
    __builtin_amdgcn_sched_barrier(0);
}

// ---------------- row-local (16-lane) DPP helpers ----------------
template<int CTRL>
__device__ __forceinline__ double dpp_d(double v){
    long long x = __double_as_longlong(v);
    int lo = __builtin_amdgcn_update_dpp((int)(u32)x, (int)(u32)x, CTRL, 0xF, 0xF, false);
    int hi = __builtin_amdgcn_update_dpp((int)(u32)(x >> 32), (int)(u32)(x >> 32), CTRL, 0xF, 0xF, false);
    return __longlong_as_double((long long)(((u64)(u32)hi << 32) | (u32)lo));
}
template<int CTRL>
__device__ __forceinline__ double dmaxd(double v){
    double o = dpp_d<CTRL>(v);
    return fmax(v, o);
}
template<int CTRL>
__device__ __forceinline__ float dmaxf(float v){
    int o = __builtin_amdgcn_update_dpp(__float_as_int(v), __float_as_int(v), CTRL, 0xF, 0xF, false);
    return fmaxf(v, __int_as_float(o));
}
__device__ __forceinline__ double rowmax_d(double v){
    v = dmaxd<0xB1>(v); v = dmaxd<0x4E>(v); v = dmaxd<0x141>(v); v = dmaxd<0x140>(v);
    return v;
}
__device__ __forceinline__ float rowmax_f(float v){
    v = dmaxf<0xB1>(v); v = dmaxf<0x4E>(v); v = dmaxf<0x141>(v); v = dmaxf<0x140>(v);
    return v;
}
// one tournament-merge level: s (sorted desc 16) <- sorted top-16 of union
// with DPP partner's list. Half-clean (Batcher) + 4-stage bitonic clean.
template<int CTRL>
__device__ __forceinline__ void merge16(double* s){
    double b[16];
    #pragma unroll
    for (int j = 0; j < 16; ++j) b[j] = dpp_d<CTRL>(s[j]);
    double c[16];
    #pragma unroll
    for (int j = 0; j < 16; ++j) c[j] = fmax(s[j], b[15 - j]);   // top-16 set, bitonic
    #pragma unroll
    for (int d = 8; d; d >>= 1){
        #pragma unroll
        for (int i = 0; i < 16; ++i){
            if ((i & d) == 0){
                double hi = fmax(c[i], c[i + d]);
                double lo = fmin(c[i], c[i + d]);
                c[i] = hi; c[i + d] = lo;
            }
        }
    }
    #pragma unroll
    for (int j = 0; j < 16; ++j) s[j] = c[j];
}

__global__ __launch_bounds__(128)
void ctc_beam(const float* __restrict__ in, float* __restrict__ out)
{
    __shared__ __align__(16) float ring[8][2][VPAD];   // [buf][ex][c] (4-step batching)
    __shared__ __align__(8)  float2 srtS[8][2][17];    // [buf][ex][rank]
    __shared__ __align__(16) float evS[4][VPAD];       // [unit][c] producer-private
    __shared__ float lsS[4];
    __shared__ float2 stateF2[2][BWID];                // {npb, staynb}
    __shared__ int2   lastlenS[2][BWID];               // {last, len}
    __shared__ unsigned short bp[2][TSTEPS][BWID];     // backpointers (32 KB)
    __shared__ float finalsS[2][BWID];

    const int tid  = threadIdx.x;
    const int wid  = tid >> 6;                      // 0 = consumer, 1 = producer
    const int lane = tid & 63;
    const int rl   = lane & 15;                     // lane within 16-lane row
    const int eh   = (lane >> 4) & 1;               // consumer example (dup on lanes 32-63)
    const int bm   = rl;                            // beam this lane owns
    const int unit = lane >> 4;                     // producer unit 0..3
    const int pex  = unit & 1;                      // unit's example
    const int pdt  = unit >> 1;                     // unit's row offset (0 or 1)
    const int bex  = blockIdx.x * 2 + eh;
    const int pbex = blockIdx.x * 2 + pex;
    const float* __restrict__ prow = in + (size_t)pbex * TSTEPS * VCLS;

    float pb_r = NEGF, pnb_r = NEGF;
    int last_r = -1, len_r = 0;

    float xv[6], xw[6];                             // producer prefetch regs (2 rows)

    auto LOADROW = [&](int r, float* dst){
        const float* p = prow + (size_t)r * VCLS + rl;
        #pragma unroll
        for (int j = 0; j < 6; ++j) dst[j] = p[j * 16];
    };
    auto PRODUCE = [&](int buf, const float* x){
        float lm = fmaxf(fmaxf(fmaxf(x[0], x[1]), fmaxf(x[2], x[3])), fmaxf(x[4], x[5]));
        float m = rowmax_f(lm);
        float sh[6];
        #pragma unroll
        for (int j = 0; j < 6; ++j){
            sh[j] = __fsub_rn(x[j], m);
            evS[unit][j * 16 + rl] = exp_xla(sh[j]);
        }
        wave_fence();
        if (rl == 0){
            float s = 0.0f;                          // strict in-order reduce, init 0
            const float4* e4 = (const float4*)evS[unit];
            #pragma unroll
            for (int g = 0; g < 24; ++g){
                float4 w = e4[g];
                s = __fadd_rn(s, w.x); s = __fadd_rn(s, w.y);
                s = __fadd_rn(s, w.z); s = __fadd_rn(s, w.w);
            }
            lsS[unit] = log_xla(s);
        }
        wave_fence();
        float ls = lsS[unit];
        double kk[6];
        #pragma unroll
        for (int j = 0; j < 6; ++j){
            float lp = __fsub_rn(sh[j], ls);
            ring[buf][pex][j * 16 + rl] = lp;
            int c = j * 16 + rl;
            kk[j] = (c == CCLS) ? 0.0 : packlp(lp, c);
        }
        double t0 = fmax(kk[0], kk[1]), t1 = fmax(kk[2], kk[3]), t2 = fmax(kk[4], kk[5]);
        double pl = fmax(fmax(t0, t1), t2);
        #pragma unroll 1
        for (int i = 0; i < 17; ++i){                // top-17, stable (ties -> ascending c)
            double wk = rowmax_d(pl);
            if (rl == 0){
                u64 bits = (u64)__double_as_longlong(wk);
                int c = (int)((~(u32)(bits >> 24)) & 0x7Fu);
                srtS[buf][pex][i] = make_float2(unford((u32)(bits >> 31)), __int_as_float(c));
            }
            long long wkb = __double_as_longlong(wk);
            #pragma unroll
            for (int j = 0; j < 6; ++j)
                kk[j] = (__double_as_longlong(kk[j]) == wkb) ? 0.0 : kk[j];
            double u0 = fmax(kk[0], kk[1]), u1 = fmax(kk[2], kk[3]), u2 = fmax(kk[4], kk[5]);
            pl = fmax(fmax(u0, u1), u2);
        }
    };

    // ---- prologue ----
    if (wid == 1){
        LOADROW(pdt, xv);
        PRODUCE(pdt, xv);
        LOADROW(2 + pdt, xv);
        PRODUCE(2 + pdt, xv);
        LOADROW(4 + pdt, xv);
        LOADROW(6 + pdt, xw);
    } else {
        pb_r = (bm == 0) ? 0.0f : NEGF;
        pnb_r = NEGF; last_r = -1; len_r = 0;
        if (lane < 32){
            lastlenS[eh][bm] = make_int2(-1, 0);
        }
    }
    __syncthreads();

    auto STEP = [&](int t){
        const float*  __restrict__ lpc = ring[t & 7][eh];
        const float2* __restrict__ srt = srtS[t & 7][eh];

        // early LDS loads
        float sv[17]; int scv[17];
        #pragma unroll
        for (int j = 0; j < 17; ++j){
            float2 e = srt[j];
            sv[j] = e.x; scv[j] = __float_as_int(e.y);
        }
        float lpb = lpc[CCLS];
        float lpl = lpc[(last_r >= 0) ? last_r : 0];

        // ---- step 2: per-beam precompute ----
        float pt  = logaddexp_x(pb_r, pnb_r);
        float npb = pt + lpb;
        float stnb = (last_r >= 0) ? (pnb_r + lpl) : NEGF;
        float stay = logaddexp_x(npb, stnb);
        if (lane < 32){
            stateF2[eh][bm] = make_float2(npb, stnb);
        }

        // ---- stream build, parallel: raw keys, skip position, insert ins ----
        const int idx0 = BWID + bm * CCLS;
        double ins = (last_r >= 0) ? packkey(__fadd_rn(pb_r, lpl), idx0 + last_r) : 0.0;
        double raw[17];
        #pragma unroll
        for (int j = 0; j < 17; ++j)
            raw[j] = packkey(__fadd_rn(pt, sv[j]), idx0 + scv[j]);
        u32 mq = 0;
        #pragma unroll
        for (int j = 0; j < 17; ++j) mq |= (scv[j] == last_r) ? (1u << j) : 0u;
        int tpos = mq ? __builtin_ctz(mq) : 99;      // at most one match (chars distinct)
        double st[16];
        {
            double f0 = (0 < tpos) ? raw[0] : raw[1];
            bool g0 = f0 > ins;
            st[0] = g0 ? f0 : ins;
            bool gprev = g0;
            double fprev = f0;
            #pragma unroll
            for (int j = 1; j < 16; ++j){
                double fj = (j < tpos) ? raw[j] : raw[j + 1];
                bool g = fj > ins;
                st[j] = g ? fj : (gprev ? ins : fprev);
                gprev = g; fprev = fj;
            }
        }

        // ---- TIE REPAIR: 4 odd-even phases (sorts any <=3-run, both parities) ----
        #pragma unroll
        for (int ph = 0; ph < 4; ++ph){
            #pragma unroll
            for (int j = (ph & 1); j < 15; j += 2){
                double a = st[j], bk = st[j + 1];
                bool sw = a < bk;
                st[j]     = sw ? bk : a;
                st[j + 1] = sw ? a : bk;
            }
        }

        // ---- insert stay into sorted stream, truncate to 16 ----
        double stay_k = packkey(stay, bm);
        double stb[16];
        {
            bool gprev = true;
            double sprev = 0.0;
            #pragma unroll
            for (int j = 0; j < 16; ++j){
                bool g = st[j] > stay_k;
                stb[j] = g ? st[j] : (gprev ? stay_k : sprev);
                gprev = g; sprev = st[j];
            }
        }

        // ---- 4 bitonic tournament-merge levels -> global sorted top-16 in stb ----
        merge16<0xB1>(stb);    // xor1
        merge16<0x4E>(stb);    // xor2
        merge16<0x141>(stb);   // row_half_mirror (pairs 4-groups within 8)
        merge16<0x140>(stb);   // row_mirror (pairs 8-groups within 16)

        // ---- beam bm extracts rank bm via static select tree ----
        double v01[8];
        #pragma unroll
        for (int j = 0; j < 8; ++j) v01[j] = (bm & 1) ? stb[2 * j + 1] : stb[2 * j];
        double v2[4];
        #pragma unroll
        for (int j = 0; j < 4; ++j) v2[j] = (bm & 2) ? v01[2 * j + 1] : v01[2 * j];
        double v4[2];
        #pragma unroll
        for (int j = 0; j < 2; ++j) v4[j] = (bm & 4) ? v2[2 * j + 1] : v2[2 * j];
        double win = (bm & 8) ? v4[1] : v4[0];
        int mysel = decodekey(win);
        float myscore = unford((u32)((u64)__double_as_longlong(win) >> 31));

        // ---- step 5: new state for own (eh,bm) ----
        wave_fence();
        int nlast, nlen, parent, code;
        float npbV, npnbV;
        {
            int s = mysel;
            if (s < BWID){                           // stay
                parent = s; code = 0;
                float2 f2 = stateF2[eh][s];
                int2 i2 = lastlenS[eh][s];
                nlast = i2.x; nlen = i2.y;
                npbV = f2.x; npnbV = f2.y;
            } else {                                 // extend: score from the key
                u32 e = (u32)(s - BWID);
                parent = (int)((e * 44151u) >> 22);  // exact e/95 for e<1520
                int c = (int)(e - (u32)parent * 95u);
                code = c + 1;
                nlast = c;
                int2 i2 = lastlenS[eh][parent];
                nlen = i2.y + 1;
                npbV = NEGF;
                npnbV = myscore;                     // == bs + lp[c], exact (from packed key)
            }
        }
        __builtin_amdgcn_sched_barrier(0);
        pb_r = npbV; pnb_r = npnbV; last_r = nlast; len_r = nlen;
        if (lane < 32){
            lastlenS[eh][bm] = make_int2(nlast, nlen);
            bp[eh][t][bm] = (unsigned short)((parent << 8) | code);
        }
    };

    for (int k = 0; k < TSTEPS / 4; ++k){
        if (wid == 1){
            if (k + 1 < TSTEPS / 4){
                float cx[6], cy[6];
                #pragma unroll
                for (int j = 0; j < 6; ++j){ cx[j] = xv[j]; cy[j] = xw[j]; }
                if (k + 2 < TSTEPS / 4){
                    LOADROW(4 * k + 8 + pdt, xv);
                    LOADROW(4 * k + 10 + pdt, xw);
                }
                #pragma unroll 1
                for (int s = 0; s < 2; ++s){
                    float cc[6];
                    #pragma unroll
                    for (int j = 0; j < 6; ++j) cc[j] = s ? cy[j] : cx[j];
                    PRODUCE((4 * k + 4 + 2 * s + pdt) & 7, cc);
                }
            }
        } else {
            #pragma unroll 1
            for (int s = 0; s < 4; ++s) STEP(4 * k + s);
        }
        __syncthreads();
    }

    // ---- final: consumer wave, lanes 0-31 ----
    if (wid == 0){
        if (lane < 32) finalsS[eh][bm] = logaddexp_x(pb_r, pnb_r);
        wave_fence();
        int bi_loc = 0;
        if (rl == 0 && lane < 32){
            float bv = finalsS[eh][0];
            for (int i = 1; i < BWID; ++i){
                if (finalsS[eh][i] > bv){ bv = finalsS[eh][i]; bi_loc = i; }
            }
            out[(size_t)NBATCH * TSTEPS + bex] = exp_xla(bv);   // probability
        }
        int biA = __builtin_amdgcn_readlane(bi_loc, 0);
        int biB = __builtin_amdgcn_readlane(bi_loc, 16);
        int bi = eh ? biB : biA;
        int L  = lastlenS[eh][bi].y;
        if (lane < 32){
            for (int j = L + rl; j < TSTEPS; j += 16) out[(size_t)bex * TSTEPS + j] = -1.0f;
        }
        if (rl == 0 && lane < 32){
            int beam = bi, pos = L;
            for (int t = TSTEPS - 1; t >= 0; --t){
                unsigned short e = bp[eh][t][beam];
                int code = e & 0xFF;
                if (code){ out[(size_t)bex * TSTEPS + (pos - 1)] = (float)(code - 1); pos--; }
                beam = e >> 8;
            }
        }
    }
}

extern "C" void kernel_launch(void* const* d_in, const int* in_sizes, int n_in,
                              void* d_out, int out_size, void* d_ws, size_t ws_size,
                              hipStream_t stream)
{
    const float* in = (const float*)d_in[0];
    float* out = (float*)d_out;
    hipLaunchKernelGGL(ctc_beam, dim3(NBATCH / 2), dim3(128), 0, stream, in, out);
}

// Round 24
// 1639.178 us; speedup vs baseline: 1.2813x; 1.2813x over previous
//
#include <hip/hip_runtime.h>
#include <math.h>

// CTC prefix beam search, TWO examples per block, 16-LANE-ROW layout.
// FINAL-RESTORE = R19 (best measured: 1640.8 us, absmax 0.0): bounded
// winner-shift (full-unroll rounds), extend-score decoded from winner key,
// padded LDS rows (104), 4-step batching (ring[8]).
// R22 (parallel-build+top2) was null; R23 (bitonic sort) regressed (scratch
// spill) -> "deep-but-thin" serial rounds are the local optimum here.
// Numerics replicate XLA:CPU f32 op-for-op (verified absmax 0.0 r3-r23).
#define NBATCH 512
#define TSTEPS 512
#define VCLS   96
#define CCLS   95
#define BWID   16
#define VPAD   104
#define NEGF   (-1e30f)

typedef unsigned long long u64;
typedef unsigned int u32;

// ---------------- XLA:CPU-replica transcendentals (no FMA, explicit rounding) ----------------
__device__ __forceinline__ float exp_xla(float x){
    x = fminf(x, 88.3762626647950f);
    x = fmaxf(x, -88.3762626647949f);
    float t = __fadd_rn(__fmul_rn(x, 1.44269504088896341f), 0.5f);
    float m = floorf(t);
    float r = __fadd_rn(__fmul_rn(m, -0.693359375f), x);
    r = __fadd_rn(__fmul_rn(m, 2.12194440e-4f), r);
    float y = 1.9875691500E-4f;
    y = __fadd_rn(__fmul_rn(y, r), 1.3981999507E-3f);
    y = __fadd_rn(__fmul_rn(y, r), 8.3334519073E-3f);
    y = __fadd_rn(__fmul_rn(y, r), 4.1665795894E-2f);
    y = __fadd_rn(__fmul_rn(y, r), 1.6666665459E-1f);
    y = __fadd_rn(__fmul_rn(y, r), 5.0000001201E-1f);
    float r2 = __fmul_rn(r, r);
    y = __fadd_rn(__fmul_rn(y, r2), r);
    y = __fadd_rn(y, 1.0f);
    int n = (int)m;
    unsigned sb = (unsigned)(n + 127);
    float s = __uint_as_float(sb << 23);
    return __fmul_rn(y, s);
}

__device__ __forceinline__ float log_xla(float x){
    unsigned bits = __float_as_uint(x);
    int e = (int)(bits >> 23) - 126;
    float m = __uint_as_float((bits & 0x007FFFFFu) | 0x3F000000u);
    if (m < 0.707106781186547524f){
        e -= 1;
        m = __fsub_rn(__fadd_rn(m, m), 1.0f);
    } else {
        m = __fsub_rn(m, 1.0f);
    }
    float z = __fmul_rn(m, m);
    float p = 7.0376836292E-2f;
    p = __fadd_rn(__fmul_rn(p, m), -1.1514610310E-1f);
    p = __fadd_rn(__fmul_rn(p, m),  1.1676998740E-1f);
    p = __fadd_rn(__fmul_rn(p, m), -1.2420140846E-1f);
    p = __fadd_rn(__fmul_rn(p, m),  1.4249322787E-1f);
    p = __fadd_rn(__fmul_rn(p, m), -1.6668057665E-1f);
    p = __fadd_rn(__fmul_rn(p, m),  2.0000714765E-1f);
    p = __fadd_rn(__fmul_rn(p, m), -2.4999993993E-1f);
    p = __fadd_rn(__fmul_rn(p, m),  3.3333331174E-1f);
    float y = __fmul_rn(m, __fmul_rn(z, p));
    float fe = (float)e;
    y = __fadd_rn(y, __fmul_rn(-2.12194440e-4f, fe));
    y = __fadd_rn(y, __fmul_rn(-0.5f, z));
    float rr = __fadd_rn(m, y);
    rr = __fadd_rn(rr, __fmul_rn(0.693359375f, fe));
    return rr;
}

__device__ __forceinline__ float log1p_xla(float x){
    float u = __fadd_rn(x, 1.0f);
    if (u == 1.0f) return x;
    float lu = log_xla(u);
    float um1 = __fsub_rn(u, 1.0f);
    return __fmul_rn(lu, __fdiv_rn(x, um1));
}

__device__ __forceinline__ float logaddexp_x(float x, float y){
    float amax = fmaxf(x, y);
    float d = __fsub_rn(x, y);
    float e = exp_xla(-fabsf(d));
    float l1p = log1p_xla(e);
    return __fadd_rn(amax, l1p);
}

// monotone float -> uint (ascending); no NaN/-0 candidates by construction
__device__ __forceinline__ unsigned ford(float f){
    unsigned u = __float_as_uint(f);
    return (u & 0x80000000u) ? ~u : (u | 0x80000000u);
}
__device__ __forceinline__ float unford(u32 u){
    return __uint_as_float((u & 0x80000000u) ? (u ^ 0x80000000u) : ~u);
}

// ---------------- f64-packed selection keys ----------------
__device__ __forceinline__ double packkey(float sc, int k){
    u64 kb = ((u64)ford(sc) << 31) | ((u64)((~(u32)k) & 0x7FFu) << 20);
    return __longlong_as_double((long long)kb);
}
__device__ __forceinline__ int decodekey(double wk){
    u32 idxinv = (u32)((u64)__double_as_longlong(wk) >> 20) & 0x7FFu;
    return (int)((~idxinv) & 0x7FFu);
}
__device__ __forceinline__ double packlp(float v, int c){
    u64 kb = ((u64)ford(v) << 31) | ((u64)((~(u32)c) & 0x7Fu) << 24);
    return __longlong_as_double((long long)kb);
}

// ---------------- intra-wave LDS fence ----------------
__device__ __forceinline__ void wave_fence(){
    asm volatile("s_waitcnt lgkmcnt(0)" ::: "memory");
    __builtin_amdgcn_sched_barrier(0);
}

// ---------------- row-local (16-lane) max reduces: 4 DPP levels, pure VALU ----------------
template<int CTRL>
__device__ __forceinline__ double dmaxd(double v){
    long long x = __double_as_longlong(v);
    int lo = __builtin_amdgcn_update_dpp((int)(u32)x, (int)(u32)x, CTRL, 0xF, 0xF, false);
    int hi = __builtin_amdgcn_update_dpp((int)(u32)(x >> 32), (int)(u32)(x >> 32), CTRL, 0xF, 0xF, false);
    double o = __longlong_as_double((long long)(((u64)(u32)hi << 32) | (u32)lo));
    return fmax(v, o);
}
template<int CTRL>
__device__ __forceinline__ float dmaxf(float v){
    int o = __builtin_amdgcn_update_dpp(__float_as_int(v), __float_as_int(v), CTRL, 0xF, 0xF, false);
    return fmaxf(v, __int_as_float(o));
}
__device__ __forceinline__ double rowmax_d(double v){
    v = dmaxd<0xB1>(v);    // quad_perm xor1
    v = dmaxd<0x4E>(v);    // quad_perm xor2
    v = dmaxd<0x141>(v);   // row_half_mirror
    v = dmaxd<0x140>(v);   // row_mirror -> row-uniform
    return v;
}
__device__ __forceinline__ float rowmax_f(float v){
    v = dmaxf<0xB1>(v);
    v = dmaxf<0x4E>(v);
    v = dmaxf<0x141>(v);
    v = dmaxf<0x140>(v);
    return v;
}

__global__ __launch_bounds__(128)
void ctc_beam(const float* __restrict__ in, float* __restrict__ out)
{
    __shared__ __align__(16) float ring[8][2][VPAD];   // [buf][ex][c] (4-step batching)
    __shared__ __align__(8)  float2 srtS[8][2][17];    // [buf][ex][rank]
    __shared__ __align__(16) float evS[4][VPAD];       // [unit][c] producer-private
    __shared__ float lsS[4];
    __shared__ float2 stateF2[2][BWID];                // {npb, staynb}
    __shared__ int2   lastlenS[2][BWID];               // {last, len}
    __shared__ unsigned short bp[2][TSTEPS][BWID];     // backpointers (32 KB)
    __shared__ float finalsS[2][BWID];

    const int tid  = threadIdx.x;
    const int wid  = tid >> 6;                      // 0 = consumer, 1 = producer
    const int lane = tid & 63;
    const int rl   = lane & 15;                     // lane within 16-lane row
    const int eh   = (lane >> 4) & 1;               // consumer example (dup on lanes 32-63)
    const int bm   = rl;                            // beam this lane owns
    const int unit = lane >> 4;                     // producer unit 0..3
    const int pex  = unit & 1;                      // unit's example
    const int pdt  = unit >> 1;                     // unit's row offset (0 or 1)
    const int bex  = blockIdx.x * 2 + eh;
    const int pbex = blockIdx.x * 2 + pex;
    const float* __restrict__ prow = in + (size_t)pbex * TSTEPS * VCLS;

    float pb_r = NEGF, pnb_r = NEGF;
    int last_r = -1, len_r = 0;

    float xv[6], xw[6];                             // producer prefetch regs (2 rows)

    auto LOADROW = [&](int r, float* dst){
        const float* p = prow + (size_t)r * VCLS + rl;
        #pragma unroll
        for (int j = 0; j < 6; ++j) dst[j] = p[j * 16];
    };
    // one call: log-softmax + lp top-17 sort for one row of each example (4 units)
    auto PRODUCE = [&](int buf, const float* x){
        float lm = fmaxf(fmaxf(fmaxf(x[0], x[1]), fmaxf(x[2], x[3])), fmaxf(x[4], x[5]));
        float m = rowmax_f(lm);                      // exact own-row max
        float sh[6];
        #pragma unroll
        for (int j = 0; j < 6; ++j){
            sh[j] = __fsub_rn(x[j], m);
            evS[unit][j * 16 + rl] = exp_xla(sh[j]);
        }
        wave_fence();
        if (rl == 0){                                // lanes 0,16,32,48: 4 parallel chains
            float s = 0.0f;                          // strict in-order reduce, init 0
            const float4* e4 = (const float4*)evS[unit];
            #pragma unroll
            for (int g = 0; g < 24; ++g){
                float4 w = e4[g];
                s = __fadd_rn(s, w.x); s = __fadd_rn(s, w.y);
                s = __fadd_rn(s, w.z); s = __fadd_rn(s, w.w);
            }
            lsS[unit] = log_xla(s);
        }
        wave_fence();
        float ls = lsS[unit];
        double kk[6];
        #pragma unroll
        for (int j = 0; j < 6; ++j){
            float lp = __fsub_rn(sh[j], ls);
            ring[buf][pex][j * 16 + rl] = lp;
            int c = j * 16 + rl;
            kk[j] = (c == CCLS) ? 0.0 : packlp(lp, c);   // blank excluded
        }
        double t0 = fmax(kk[0], kk[1]), t1 = fmax(kk[2], kk[3]), t2 = fmax(kk[4], kk[5]);
        double pl = fmax(fmax(t0, t1), t2);
        #pragma unroll 1
        for (int i = 0; i < 17; ++i){                // top-17, stable (ties -> ascending c)
            double wk = rowmax_d(pl);
            if (rl == 0){
                u64 bits = (u64)__double_as_longlong(wk);
                int c = (int)((~(u32)(bits >> 24)) & 0x7Fu);
                srtS[buf][pex][i] = make_float2(unford((u32)(bits >> 31)), __int_as_float(c));
            }
            long long wkb = __double_as_longlong(wk);
            #pragma unroll
            for (int j = 0; j < 6; ++j)
                kk[j] = (__double_as_longlong(kk[j]) == wkb) ? 0.0 : kk[j];
            double u0 = fmax(kk[0], kk[1]), u1 = fmax(kk[2], kk[3]), u2 = fmax(kk[4], kk[5]);
            pl = fmax(fmax(u0, u1), u2);
        }
    };

    // ---- prologue ----
    if (wid == 1){
        LOADROW(pdt, xv);
        PRODUCE(pdt, xv);                            // steps 0,1
        LOADROW(2 + pdt, xv);
        PRODUCE(2 + pdt, xv);                        // steps 2,3
        LOADROW(4 + pdt, xv);                        // prefetch steps 4,5
        LOADROW(6 + pdt, xw);                        // prefetch steps 6,7
    } else {
        pb_r = (bm == 0) ? 0.0f : NEGF;
        pnb_r = NEGF; last_r = -1; len_r = 0;
        if (lane < 32){
            lastlenS[eh][bm] = make_int2(-1, 0);
        }
    }
    __syncthreads();

    auto STEP = [&](int t){
        const float*  __restrict__ lpc = ring[t & 7][eh];
        const float2* __restrict__ srt = srtS[t & 7][eh];

        // ---- step 2: per-beam precompute (every lane, own (eh,bm)) ----
        float lpb = lpc[CCLS];
        float lpl = lpc[(last_r >= 0) ? last_r : 0];
        float pt  = logaddexp_x(pb_r, pnb_r);
        float npb = pt + lpb;
        float stnb = (last_r >= 0) ? (pnb_r + lpl) : NEGF;
        float stay = logaddexp_x(npb, stnb);
        if (lane < 32){
            stateF2[eh][bm] = make_float2(npb, stnb);
        }

        // ---- sorted ext stream st[0..15] (fused filter+insert) ----
        const int idx0 = BWID + bm * CCLS;
        double ins = (last_r >= 0) ? packkey(__fadd_rn(pb_r, lpl), idx0 + last_r) : 0.0;
        double st[16];
        {
            float2 e0 = srt[0];
            int c0 = __float_as_int(e0.y);
            double raw_c = packkey(__fadd_rn(pt, e0.x), idx0 + c0);
            bool seen = (c0 == last_r);
            bool gtprev = true;
            double flt_prev = 0.0;
            #pragma unroll
            for (int j = 0; j < 16; ++j){
                float2 en = srt[j + 1];
                int cn = __float_as_int(en.y);
                double raw_n = packkey(__fadd_rn(pt, en.x), idx0 + cn);
                double flt_j = seen ? raw_n : raw_c;         // filter out repeat char
                bool gt = (flt_j > ins);
                st[j] = gt ? flt_j : (gtprev ? ins : flt_prev);  // sorted insert
                gtprev = gt; flt_prev = flt_j;
                raw_c = raw_n;
                seen = seen | (cn == last_r);
            }
        }

        // ---- TIE REPAIR: bit-equal sums order by ~idx; 2 bubble passes ----
        #pragma unroll
        for (int p = 0; p < 2; ++p){
            #pragma unroll
            for (int j = 0; j < 15; ++j){
                double a = st[j], bk = st[j + 1];
                bool sw = a < bk;
                st[j]     = sw ? bk : a;
                st[j + 1] = sw ? a : bk;
            }
        }

        // ---- 16 argmax rounds, fully unrolled; shift bound shrinks with r ----
        double stay_k = packkey(stay, bm);
        int mysel = 0;
        float myscore = 0.0f;
        #pragma unroll
        for (int r = 0; r < BWID; ++r){
            double loc = fmax(stay_k, st[0]);
            double wk = rowmax_d(loc);             // own example's global max, every lane
            if (bm == r){
                mysel = decodekey(wk);
                myscore = unford((u32)((u64)__double_as_longlong(wk) >> 31));
            }
            if (r < BWID - 1){
                long long wkb = __double_as_longlong(wk);
                bool winstay = (__double_as_longlong(stay_k) == wkb);
                bool winst   = (__double_as_longlong(st[0]) == wkb);
                stay_k = winstay ? 0.0 : stay_k;
                // only depths 0..(15-r-1) can be consumed by the remaining rounds
                #pragma unroll
                for (int j = 0; j < BWID - 1 - r; ++j) st[j] = winst ? st[j + 1] : st[j];
            }
        }

        // ---- step 5: new state for own (eh,bm) ----
        wave_fence();                              // step-2 LDS writes -> cross-beam reads
        int nlast, nlen, parent, code;
        float npbV, npnbV;
        {
            int s = mysel;
            if (s < BWID){                         // stay
                parent = s; code = 0;
                float2 f2 = stateF2[eh][s];
                int2 i2 = lastlenS[eh][s];
                nlast = i2.x; nlen = i2.y;
                npbV = f2.x; npnbV = f2.y;
            } else {                               // extend: score comes from the key
                u32 e = (u32)(s - BWID);
                parent = (int)((e * 44151u) >> 22);        // exact e/95 for e<1520
                int c = (int)(e - (u32)parent * 95u);
                code = c + 1;
                nlast = c;
                int2 i2 = lastlenS[eh][parent];
                nlen = i2.y + 1;
                npbV = NEGF;
                npnbV = myscore;                   // == bs + lp[c], exact (from packed key)
            }
        }
        __builtin_amdgcn_sched_barrier(0);         // pin reads before the writes below
        pb_r = npbV; pnb_r = npnbV; last_r = nlast; len_r = nlen;
        if (lane < 32){
            lastlenS[eh][bm] = make_int2(nlast, nlen);
            bp[eh][t][bm] = (unsigned short)((parent << 8) | code);
        }
    };

    for (int k = 0; k < TSTEPS / 4; ++k){
        if (wid == 1){
            if (k + 1 < TSTEPS / 4){
                float cx[6], cy[6];
                #pragma unroll
                for (int j = 0; j < 6; ++j){ cx[j] = xv[j]; cy[j] = xw[j]; }
                if (k + 2 < TSTEPS / 4){           // prefetch batch k+1's rows
                    LOADROW(4 * k + 8 + pdt, xv);
                    LOADROW(4 * k + 10 + pdt, xw);
                }
                PRODUCE((4 * k + 4 + pdt) & 7, cx);
                PRODUCE((4 * k + 6 + pdt) & 7, cy);
            }
        } else {
            STEP(4 * k);
            STEP(4 * k + 1);
            STEP(4 * k + 2);
            STEP(4 * k + 3);
        }
        __syncthreads();
    }

    // ---- final: consumer wave, lanes 0-31 ----
    if (wid == 0){
        if (lane < 32) finalsS[eh][bm] = logaddexp_x(pb_r, pnb_r);
        wave_fence();
        int bi_loc = 0;
        if (rl == 0 && lane < 32){                 // lanes 0 (eh0) and 16 (eh1)
            float bv = finalsS[eh][0];
            for (int i = 1; i < BWID; ++i){
                if (finalsS[eh][i] > bv){ bv = finalsS[eh][i]; bi_loc = i; }
            }
            out[(size_t)NBATCH * TSTEPS + bex] = exp_xla(bv);   // probability
        }
        int biA = __builtin_amdgcn_readlane(bi_loc, 0);
        int biB = __builtin_amdgcn_readlane(bi_loc, 16);
        int bi = eh ? biB : biA;
        int L  = lastlenS[eh][bi].y;
        if (lane < 32){
            for (int j = L + rl; j < TSTEPS; j += 16) out[(size_t)bex * TSTEPS + j] = -1.0f;
        }
        if (rl == 0 && lane < 32){
            int beam = bi, pos = L;
            for (int t = TSTEPS - 1; t >= 0; --t){
                unsigned short e = bp[eh][t][beam];
                int code = e & 0xFF;
                if (code){ out[(size_t)bex * TSTEPS + (pos - 1)] = (float)(code - 1); pos--; }
                beam = e >> 8;
            }
        }
    }
}

extern "C" void kernel_launch(void* const* d_in, const int* in_sizes, int n_in,
                              void* d_out, int out_size, void* d_ws, size_t ws_size,
                              hipStream_t stream)
{
    const float* in = (const float*)d_in[0];
    float* out = (float*)d_out;
    hipLaunchKernelGGL(ctc_beam, dim3(NBATCH / 2), dim3(128), 0, stream, in, out);
}